// Round 18
// baseline (178.968 us; speedup 1.0000x reference)
//
#include <hip/hip_runtime.h>
#include <hip/hip_bf16.h>

#define S_LEN 4096
#define BATCH 4
#define DMODEL 1024
#define HDIM 128
#define NSLOT 8   // KV chunk slots (fixed chunk = 8 kv-blocks = 512 kv)

typedef __attribute__((ext_vector_type(8))) short short8;
typedef __attribute__((ext_vector_type(4))) short short4v;
typedef __attribute__((ext_vector_type(4))) float float4v;
typedef __attribute__((ext_vector_type(16))) float float16v;
typedef __attribute__((ext_vector_type(4))) int int4v;

#define MASKVAL (-3.0e38f)
#define MINIT   (-1.0e30f)

static __device__ __forceinline__ unsigned short f2bf(float f) {
    __hip_bfloat16 h = __float2bfloat16(f);
    return *reinterpret_cast<unsigned short*>(&h);
}
static __device__ __forceinline__ unsigned short f2h(float f) {
    _Float16 h = (_Float16)f; return *reinterpret_cast<unsigned short*>(&h);
}
static __device__ __forceinline__ float h2f(unsigned short u) {
    _Float16 h = *reinterpret_cast<_Float16*>(&u); return (float)h;
}
static __device__ __forceinline__ short8 ldf(const unsigned short* p) {
    return *reinterpret_cast<const short8*>(p);
}
// raw v_exp_f32: 2^x in one hazard-aware instruction (scores are in log2 units)
static __device__ __forceinline__ float ex2(float x) {
    return __builtin_amdgcn_exp2f(x);
}
// async global->LDS 16B/lane copy of one 1KB fragment (wave-wide)
static __device__ __forceinline__ void gll16(const unsigned short* g,
                                             unsigned short* l) {
    __builtin_amdgcn_global_load_lds(
        (const __attribute__((address_space(1))) unsigned int*)g,
        (__attribute__((address_space(3))) unsigned int*)l, 16, 0, 0);
}
// pack 8 P-values (one 32-kv window half per lane-pair) into MFMA B-frag
static __device__ __forceinline__ short8 pack_p(const float* pv, int hi) {
    unsigned int A  = (unsigned int)f2bf(pv[0]) | ((unsigned int)f2bf(pv[1]) << 16);
    unsigned int Bw = (unsigned int)f2bf(pv[2]) | ((unsigned int)f2bf(pv[3]) << 16);
    unsigned int C  = (unsigned int)f2bf(pv[4]) | ((unsigned int)f2bf(pv[5]) << 16);
    unsigned int D  = (unsigned int)f2bf(pv[6]) | ((unsigned int)f2bf(pv[7]) << 16);
    unsigned int y1 = (unsigned int)__shfl_xor((int)(hi ? A : C), 32);
    unsigned int y2 = (unsigned int)__shfl_xor((int)(hi ? Bw : D), 32);
    int4v pw;
    pw[0] = (int)(hi ? y1 : A);
    pw[1] = (int)(hi ? y2 : Bw);
    pw[2] = (int)(hi ? C : y1);
    pw[3] = (int)(hi ? D : y2);
    union { int4v iv; short8 s; } pu; pu.iv = pw;
    return pu.s;
}

// ---------------------------------------------------------------------------
// Kernel P1: x (S,B,D) fp32 -> xf fragment-linear bf16 (output-coalesced).
// ---------------------------------------------------------------------------
__global__ __launch_bounds__(256) void xprep_kernel(
    const float* __restrict__ x, unsigned short* __restrict__ xf)
{
    int n = blockIdx.x * 256 + threadIdx.x;   // 524288 threads
    int b = n >> 17;
    int rem = n & 131071;
    int sb = rem >> 10;
    int rem2 = rem & 1023;
    int kq = rem2 >> 4;
    int grp = rem2 & 15;
    int lane0 = grp * 4;
    int par = grp >> 3;
    int s0 = lane0 & 31;
    int k = kq * 16 + par * 8;

    short8 hv[4];
#pragma unroll
    for (int r = 0; r < 4; r++) {
        int s = sb * 32 + s0 + r;
        const float* src = &x[((size_t)s * BATCH + b) * DMODEL + k];
        float4 v0 = *reinterpret_cast<const float4*>(src);
        float4 v1 = *reinterpret_cast<const float4*>(src + 4);
        short8 h;
        h[0] = (short)f2bf(v0.x); h[1] = (short)f2bf(v0.y);
        h[2] = (short)f2bf(v0.z); h[3] = (short)f2bf(v0.w);
        h[4] = (short)f2bf(v1.x); h[5] = (short)f2bf(v1.y);
        h[6] = (short)f2bf(v1.z); h[7] = (short)f2bf(v1.w);
        hv[r] = h;
    }
    size_t addr = (((size_t)b * 128 + sb) * 64 + kq) * 512 + (size_t)lane0 * 8;
#pragma unroll
    for (int r = 0; r < 4; r++)
        *reinterpret_cast<short8*>(xf + addr + r * 8) = hv[r];
}

// ---------------------------------------------------------------------------
// Kernel P2: W (H,D) fp32 -> fragment-linear bf16.
// ---------------------------------------------------------------------------
__global__ __launch_bounds__(256) void wprep_kernel(
    const float* __restrict__ Wq, const float* __restrict__ Wk,
    const float* __restrict__ Wv, unsigned short* __restrict__ Wqf,
    unsigned short* __restrict__ Wkf, unsigned short* __restrict__ Wvf)
{
    const int which = blockIdx.y;
    const float* W = (which == 0) ? Wq : (which == 1) ? Wk : Wv;
    unsigned short* Wf = (which == 0) ? Wqf : (which == 1) ? Wkf : Wvf;
    int n = blockIdx.x * 256 + threadIdx.x;   // 16384
    int d = n >> 7, k8 = n & 127;
    const float* src = &W[(size_t)d * DMODEL + k8 * 8];
    float4 v0 = *reinterpret_cast<const float4*>(src);
    float4 v1 = *reinterpret_cast<const float4*>(src + 4);
    short8 h;
    h[0] = (short)f2bf(v0.x); h[1] = (short)f2bf(v0.y);
    h[2] = (short)f2bf(v0.z); h[3] = (short)f2bf(v0.w);
    h[4] = (short)f2bf(v1.x); h[5] = (short)f2bf(v1.y);
    h[6] = (short)f2bf(v1.z); h[7] = (short)f2bf(v1.w);
    size_t addr = (((size_t)(d >> 5)) * 64 + (k8 >> 1)) * 512
                + (size_t)(((d & 31) + 32 * (k8 & 1)) * 8);
    *reinterpret_cast<short8*>(Wf + addr) = h;
}

// ---------------------------------------------------------------------------
// Kernel A: fused QKV GEMM — split-N x split-K=2 (R17 verified).
// Q scale folds head_dim^-0.5 AND log2(e).
// ---------------------------------------------------------------------------
__global__ __launch_bounds__(256) void qkv_gemm_kernel(
    const unsigned short* __restrict__ xf, const unsigned short* __restrict__ Wqf,
    const unsigned short* __restrict__ Wkf, const unsigned short* __restrict__ Wvf,
    unsigned short* __restrict__ Qf, unsigned short* __restrict__ Kf,
    unsigned short* __restrict__ Vf)
{
    __shared__ float cacc[4096];              // 16KB: 2 dhalf x 32s x 64d fp32

    const int t = threadIdx.x;
    const int w = t >> 6;
    const int lane = t & 63;
    const int hi = lane >> 5;
    const int dhalf = w & 1;
    const int khalf = w >> 1;
    const int tile = blockIdx.x;              // 0..1535
    const int which = tile >> 9;
    const int rem = tile & 511;
    const int b = rem >> 7;
    const int sblk = rem & 127;

    const unsigned short* Wf = (which == 0) ? Wqf : (which == 1) ? Wkf : Wvf;
    const unsigned short* xp =
        xf + (((size_t)b * 128 + sblk) * 64 + khalf * 32) * 512 + lane * 8;
    const unsigned short* wp =
        Wf + (size_t)(dhalf * 128 + khalf * 32) * 512 + lane * 8;

    float16v acc[2];
#pragma unroll
    for (int i = 0; i < 2; i++)
#pragma unroll
        for (int r = 0; r < 16; r++) acc[i][r] = 0.f;

    {
        short8 xA = ldf(xp);
        short8 wA[2];
#pragma unroll
        for (int dd = 0; dd < 2; dd++) wA[dd] = ldf(wp + (size_t)(dd * 64) * 512);
        for (int ks = 0; ks < 32; ks++) {
            short8 xB = xA;
            short8 wB[2];
#pragma unroll
            for (int dd = 0; dd < 2; dd++) wB[dd] = wA[dd];
            if (ks < 31) {
                xB = ldf(xp + (ks + 1) * 512);
#pragma unroll
                for (int dd = 0; dd < 2; dd++)
                    wB[dd] = ldf(wp + (size_t)(dd * 64 + ks + 1) * 512);
            }
            __builtin_amdgcn_s_setprio(1);
            if (which != 2) {
#pragma unroll
                for (int dd = 0; dd < 2; dd++)
                    acc[dd] = __builtin_amdgcn_mfma_f32_32x32x16_bf16(
                        wA[dd], xA, acc[dd], 0, 0, 0);
            } else {
#pragma unroll
                for (int dd = 0; dd < 2; dd++)
                    acc[dd] = __builtin_amdgcn_mfma_f32_32x32x16_bf16(
                        xA, wA[dd], acc[dd], 0, 0, 0);
            }
            __builtin_amdgcn_s_setprio(0);
            xA = xB;
#pragma unroll
            for (int dd = 0; dd < 2; dd++) wA[dd] = wB[dd];
        }
    }

    float* my = cacc + dhalf * 2048;
    if (khalf == 1) {
#pragma unroll
        for (int dd = 0; dd < 2; dd++)
#pragma unroll
            for (int rc = 0; rc < 4; rc++) {
                float4v v;
#pragma unroll
                for (int j = 0; j < 4; j++) v[j] = acc[dd][rc * 4 + j];
                *reinterpret_cast<float4v*>(
                    my + (dd * 4 + rc) * 256 + lane * 4) = v;
            }
    }
    __syncthreads();
    if (khalf != 0) return;

#pragma unroll
    for (int dd = 0; dd < 2; dd++)
#pragma unroll
        for (int rc = 0; rc < 4; rc++) {
            float4v v = *reinterpret_cast<const float4v*>(
                my + (dd * 4 + rc) * 256 + lane * 4);
#pragma unroll
            for (int j = 0; j < 4; j++) acc[dd][rc * 4 + j] += v[j];
        }

    if (which != 2) {
        unsigned short* Of = (which == 0) ? Qf : Kf;
        // Q: 128^-0.5 * log2(e)
        const float scale = (which == 0) ? 0.12751744f : 1.0f;
#pragma unroll
        for (int dd = 0; dd < 2; dd++) {
            int db = dhalf * 2 + dd;
#pragma unroll
            for (int g = 0; g < 4; g++) {
                int f = db * 2 + (g >> 1);
                size_t addr = (((size_t)b * 128 + sblk) * 8 + f) * 512
                            + (size_t)(((lane & 31) + 32 * (g & 1)) * 8 + 4 * hi);
                short4v ov;
#pragma unroll
                for (int j = 0; j < 4; j++)
                    ov[j] = (short)f2bf(acc[dd][g * 4 + j] * scale);
                *reinterpret_cast<short4v*>(Of + addr) = ov;
            }
        }
    } else {
#pragma unroll
        for (int dd = 0; dd < 2; dd++) {
            int hb = dhalf * 2 + dd;
#pragma unroll
            for (int g = 0; g < 4; g++) {
                int kt16 = sblk * 2 + (g >> 1);
                size_t addr = (((size_t)b * 256 + kt16) * 4 + hb) * 512
                            + (size_t)(((lane & 31) + 32 * (g & 1)) * 8 + 4 * hi);
                short4v ov;
#pragma unroll
                for (int j = 0; j < 4; j++)
                    ov[j] = (short)f2bf(acc[dd][g * 4 + j]);
                *reinterpret_cast<short4v*>(Vf + addr) = ov;
            }
        }
    }
}

// ---------------------------------------------------------------------------
// Kernel B: causal flash attention — single-buffer 32KB LDS, gll staging,
// exp2 softmax (R16/R17 verified champion).
// ---------------------------------------------------------------------------
__global__ __launch_bounds__(256) void attn_kernel(
    const unsigned short* __restrict__ Qf, const unsigned short* __restrict__ Kf,
    const unsigned short* __restrict__ Vf, unsigned short* __restrict__ Opart,
    float* __restrict__ Mpart, float* __restrict__ Lpart)
{
    __shared__ unsigned short Kb[8192];   // 16KB: 16 frags x 512
    __shared__ unsigned short Vb[8192];   // 16KB

    const int t = threadIdx.x;
    const int w = t >> 6;
    const int lane = t & 63;
    const int l31 = lane & 31;
    const int hi = lane >> 5;

    // XCD-aware decode + compact heavy-first (qt descending, real chunks only)
    const int i = blockIdx.x;                 // 0..575
    const int xx = i & 7;
    const int b = xx >> 1;
    int j = (i >> 3) * 2 + (xx & 1);          // 0..143
    int qt = 31;
    while (true) {
        int cnt = (qt + 4) >> 2;              // ceil((qt+1)/4) chunks of 8
        if (j < cnt) break;
        j -= cnt; qt--;
    }
    const int c = j;

    const int nkv = 2 * (qt + 1);
    const int lo = c * 8;
    const int hic = min(lo + 8, nkv);

    const int qb = qt * 128;
    const int qrow = qb + w * 32 + l31;

    // Q as B-fragments from Qf (frag-linear)
    const unsigned short* qp =
        Qf + (((size_t)b * 128 + (qt * 4 + w)) * 8) * 512 + lane * 8;
    short8 qf[8];
#pragma unroll
    for (int f = 0; f < 8; f++) qf[f] = ldf(qp + f * 512);

    const unsigned short* kbase =
        Kf + (size_t)b * (S_LEN / 32) * 8 * 512 + lane * 8;
    const unsigned short* vbase =
        Vf + (size_t)b * (S_LEN / 16) * 4 * 512 + lane * 8;

    float m_run = MINIT, l_run = 0.f;
    float16v o[4];
#pragma unroll
    for (int hb = 0; hb < 4; hb++)
#pragma unroll
        for (int r = 0; r < 16; r++) o[hb][r] = 0.f;

    for (int ti = lo; ti < hic; ti++) {
        const int kvb = ti * 64;
        // stage tile ti (wave w stages frags 4w..4w+3 of K and V)
        {
            const unsigned short* kg = kbase + (size_t)ti * 8192;
            const unsigned short* vg = vbase + (size_t)ti * 8192;
#pragma unroll
            for (int jj = 0; jj < 4; jj++) {
                int fi = 4 * w + jj;
                gll16(kg + fi * 512, &Kb[fi * 512]);
                gll16(vg + fi * 512, &Vb[fi * 512]);
            }
        }
        __syncthreads();   // implicit vmcnt(0): staged writes complete

        const unsigned short* Kl = &Kb[0] + lane * 8;
        const unsigned short* Vl = &Vb[0] + lane * 8;

        // S^T = K Q^T from LDS  (scores already in log2 units via Q scale)
        float16v s0, s1;
#pragma unroll
        for (int r = 0; r < 16; r++) { s0[r] = 0.f; s1[r] = 0.f; }
        __builtin_amdgcn_s_setprio(1);
#pragma unroll
        for (int f = 0; f < 8; f++)
            s0 = __builtin_amdgcn_mfma_f32_32x32x16_bf16(
                ldf(Kl + f * 512), qf[f], s0, 0, 0, 0);
#pragma unroll
        for (int f = 0; f < 8; f++)
            s1 = __builtin_amdgcn_mfma_f32_32x32x16_bf16(
                ldf(Kl + (8 + f) * 512), qf[f], s1, 0, 0, 0);
        __builtin_amdgcn_s_setprio(0);

        // causal mask (diagonal band only)
        if (kvb + 63 > qb + w * 32) {
#pragma unroll
            for (int r = 0; r < 16; r++) {
                int kv0 = kvb + (r & 3) + 8 * (r >> 2) + 4 * hi;
                if (kv0 > qrow) s0[r] = MASKVAL;
                if (kv0 + 32 > qrow) s1[r] = MASKVAL;
            }
        }

        // tree max + defer-max rescale (THR=8 in log2 units; P bounded by 256)
        float mx[16];
#pragma unroll
        for (int r = 0; r < 16; r++) mx[r] = fmaxf(s0[r], s1[r]);
#pragma unroll
        for (int st = 8; st >= 1; st >>= 1)
#pragma unroll
            for (int r = 0; r < st; r++) mx[r] = fmaxf(mx[r], mx[r + st]);
        float pmax = fmaxf(mx[0], __shfl_xor(mx[0], 32));
        if (!__all(pmax - m_run <= 8.0f)) {
            float mnew = fmaxf(m_run, pmax);
            float alpha = ex2(m_run - mnew);
            l_run *= alpha;
#pragma unroll
            for (int hb = 0; hb < 4; hb++) o[hb] = o[hb] * alpha;
            m_run = mnew;
        }
#pragma unroll
        for (int r = 0; r < 16; r++) s0[r] = ex2(s0[r] - m_run);
#pragma unroll
        for (int r = 0; r < 16; r++) s1[r] = ex2(s1[r] - m_run);
        float sm[16];
#pragma unroll
        for (int r = 0; r < 16; r++) sm[r] = s0[r] + s1[r];
#pragma unroll
        for (int st = 8; st >= 1; st >>= 1)
#pragma unroll
            for (int r = 0; r < st; r++) sm[r] += sm[r + st];
        l_run += sm[0] + __shfl_xor(sm[0], 32);

        // PV: 4 windows of 16 kv; V frags from LDS
        float t0[8], t1[8], t2[8], t3[8];
#pragma unroll
        for (int jj = 0; jj < 8; jj++) { t0[jj] = s0[jj]; t1[jj] = s0[8 + jj]; }
#pragma unroll
        for (int jj = 0; jj < 8; jj++) { t2[jj] = s1[jj]; t3[jj] = s1[8 + jj]; }

        short8 p0 = pack_p(t0, hi);
        __builtin_amdgcn_s_setprio(1);
#pragma unroll
        for (int hb = 0; hb < 4; hb++)
            o[hb] = __builtin_amdgcn_mfma_f32_32x32x16_bf16(
                ldf(Vl + (0 * 4 + hb) * 512), p0, o[hb], 0, 0, 0);
        short8 p1 = pack_p(t1, hi);
#pragma unroll
        for (int hb = 0; hb < 4; hb++)
            o[hb] = __builtin_amdgcn_mfma_f32_32x32x16_bf16(
                ldf(Vl + (1 * 4 + hb) * 512), p1, o[hb], 0, 0, 0);
        short8 p2 = pack_p(t2, hi);
#pragma unroll
        for (int hb = 0; hb < 4; hb++)
            o[hb] = __builtin_amdgcn_mfma_f32_32x32x16_bf16(
                ldf(Vl + (2 * 4 + hb) * 512), p2, o[hb], 0, 0, 0);
        short8 p3 = pack_p(t3, hi);
#pragma unroll
        for (int hb = 0; hb < 4; hb++)
            o[hb] = __builtin_amdgcn_mfma_f32_32x32x16_bf16(
                ldf(Vl + (3 * 4 + hb) * 512), p3, o[hb], 0, 0, 0);
        __builtin_amdgcn_s_setprio(0);

        __syncthreads();   // all waves done reading before next stage
    }

    // epilogue: normalized fp16 partial + (m,l);  l==0 -> zeros
    const size_t R0 = (size_t)(c * BATCH + b) * S_LEN;
    const float inv = (l_run > 0.f) ? 1.f / l_run : 0.f;
#pragma unroll
    for (int hb = 0; hb < 4; hb++)
#pragma unroll
        for (int g = 0; g < 4; g++) {
            int h0 = hb * 32 + g * 8 + hi * 4;
            short4v ov;
#pragma unroll
            for (int jj = 0; jj < 4; jj++)
                ov[jj] = (short)f2h(o[hb][g * 4 + jj] * inv);
            *reinterpret_cast<short4v*>(&Opart[(R0 + qrow) * HDIM + h0]) = ov;
        }
    if (hi == 0) { Mpart[R0 + qrow] = m_run; Lpart[R0 + qrow] = l_run; }
}

// ---------------------------------------------------------------------------
// Kernel C: output projection with INLINE combine (combine_kernel folded in).
// A-staging computes the softmax-partial merge per 8-elem chunk directly
// from Opart/Mpart/Lpart (exp2 domain), then the verified MFMA GEMM runs.
// ---------------------------------------------------------------------------
__global__ __launch_bounds__(256) void out_proj_kernel(
    const unsigned short* __restrict__ Opart, const float* __restrict__ Mpart,
    const float* __restrict__ Lpart, const float* __restrict__ Wo,
    float* __restrict__ out)
{
    __shared__ unsigned short As[128 * 128];
    __shared__ unsigned short Bs[128 * 128];

    const int t = threadIdx.x;
    const int lane = t & 63, w = t >> 6;
    const int l15 = lane & 15, l4 = lane >> 4;
    const int wr = (w >> 1) * 64, wc = (w & 1) * 64;
    const int s0 = blockIdx.x * 128;
    const int d0 = blockIdx.y * 128;
    const int b = blockIdx.z;

    const int BS = BATCH * S_LEN;
    const int qt = s0 >> 7;                  // whole 128-tile shares one qt
    const int nkv = 2 * (qt + 1);
    const int cnt = (nkv + 7) >> 3;          // # partial slots for these rows

    // stage A: inline combine of attention partials -> bf16, swizzled
#pragma unroll
    for (int p = 0; p < 8; p++) {
        int e = p * 2048 + t * 8;
        int r = e >> 7, h = e & 127;
        int row = b * S_LEN + s0 + r;        // partial row index

        float m = -INFINITY;
        for (int jj = 0; jj < cnt; jj++)
            m = fmaxf(m, Mpart[jj * BS + row]);
        float wsum = 0.f;
        float acc8[8];
#pragma unroll
        for (int e8 = 0; e8 < 8; e8++) acc8[e8] = 0.f;
        for (int jj = 0; jj < cnt; jj++) {
            float wj = ex2(Mpart[jj * BS + row] - m) * Lpart[jj * BS + row];
            wsum += wj;
            short8 ov = *reinterpret_cast<const short8*>(
                &Opart[((size_t)jj * BS + row) * HDIM + h]);
#pragma unroll
            for (int e8 = 0; e8 < 8; e8++)
                acc8[e8] += wj * h2f((unsigned short)ov[e8]);
        }
        float inv = 1.f / wsum;
        short8 v;
#pragma unroll
        for (int e8 = 0; e8 < 8; e8++) v[e8] = (short)f2bf(acc8[e8] * inv);
        int off = (r * 256 + h * 2) ^ ((r & 7) << 4);
        *reinterpret_cast<short8*>(reinterpret_cast<char*>(As) + off) = v;
    }
    // stage B: Wo tile fp32 -> bf16, swizzled
#pragma unroll
    for (int p = 0; p < 16; p++) {
        int e = p * 1024 + t * 4;
        int r = e >> 7, h = e & 127;
        float4 v = *reinterpret_cast<const float4*>(&Wo[(size_t)(d0 + r) * HDIM + h]);
        short4v hh;
        hh[0] = (short)f2bf(v.x); hh[1] = (short)f2bf(v.y);
        hh[2] = (short)f2bf(v.z); hh[3] = (short)f2bf(v.w);
        int off = (r * 256 + h * 2) ^ ((r & 7) << 4);
        *reinterpret_cast<short4v*>(reinterpret_cast<char*>(Bs) + off) = hh;
    }
    __syncthreads();

    float4v acc[4][4];
#pragma unroll
    for (int i = 0; i < 4; i++)
#pragma unroll
        for (int j = 0; j < 4; j++) acc[i][j] = (float4v){0.f, 0.f, 0.f, 0.f};

#pragma unroll
    for (int kk = 0; kk < 4; kk++) {
        short8 a[4], bf[4];
#pragma unroll
        for (int mi = 0; mi < 4; mi++) {
            int row = wr + mi * 16 + l15;
            int off = (row * 256 + (kk * 32 + l4 * 8) * 2) ^ ((row & 7) << 4);
            a[mi] = *reinterpret_cast<const short8*>(
                reinterpret_cast<const char*>(As) + off);
        }
#pragma unroll
        for (int ni = 0; ni < 4; ni++) {
            int row = wc + ni * 16 + l15;
            int off = (row * 256 + (kk * 32 + l4 * 8) * 2) ^ ((row & 7) << 4);
            bf[ni] = *reinterpret_cast<const short8*>(
                reinterpret_cast<const char*>(Bs) + off);
        }
#pragma unroll
        for (int mi = 0; mi < 4; mi++)
#pragma unroll
            for (int ni = 0; ni < 4; ni++)
                acc[mi][ni] = __builtin_amdgcn_mfma_f32_16x16x32_bf16(
                    a[mi], bf[ni], acc[mi][ni], 0, 0, 0);
    }

#pragma unroll
    for (int mi = 0; mi < 4; mi++)
#pragma unroll
        for (int ni = 0; ni < 4; ni++)
#pragma unroll
            for (int r = 0; r < 4; r++) {
                int s = s0 + wr + mi * 16 + l4 * 4 + r;
                int d = d0 + wc + ni * 16 + l15;
                out[((size_t)s * BATCH + b) * DMODEL + d] = acc[mi][ni][r];
            }
}

// ---------------------------------------------------------------------------
extern "C" void kernel_launch(void* const* d_in, const int* in_sizes, int n_in,
                              void* d_out, int out_size, void* d_ws, size_t ws_size,
                              hipStream_t stream) {
    const float* x  = (const float*)d_in[0];
    const float* Wq = (const float*)d_in[1];
    const float* Wk = (const float*)d_in[2];
    const float* Wv = (const float*)d_in[3];
    const float* Wo = (const float*)d_in[4];
    float* out = (float*)d_out;

    const size_t BS = (size_t)BATCH * S_LEN;               // 16384
    // Region 0 (32MB): xf during prep+gemm, then Opart (8 slots, disjoint lifetimes)
    unsigned short* xf    = (unsigned short*)d_ws;               // 32 MB
    unsigned short* Opart = (unsigned short*)d_ws;               // 32 MB fp16
    float* Mpart = (float*)((char*)d_ws + (32u << 20));          // 512 KB
    float* Lpart = Mpart + NSLOT * BS;                           // 512 KB
    // After 33MB:
    unsigned short* Wqf = (unsigned short*)((char*)d_ws + (33u << 20));
    unsigned short* Wkf = Wqf + 131072;
    unsigned short* Wvf = Wkf + 131072;
    unsigned short* Qf  = Wvf + 131072;                          // 4 MB each
    unsigned short* Kf  = Qf + 2097152;
    unsigned short* Vf  = Kf + 2097152;

    xprep_kernel<<<2048, 256, 0, stream>>>(x, xf);
    wprep_kernel<<<dim3(64, 3), 256, 0, stream>>>(Wq, Wk, Wv, Wqf, Wkf, Wvf);
    qkv_gemm_kernel<<<1536, 256, 0, stream>>>(xf, Wqf, Wkf, Wvf, Qf, Kf, Vf);
    attn_kernel<<<576, 256, 0, stream>>>(Qf, Kf, Vf, Opart, Mpart, Lpart);
    out_proj_kernel<<<dim3(32, 8, BATCH), 256, 0, stream>>>(Opart, Mpart, Lpart, Wo, out);
}

// Round 19
// 117.285 us; speedup vs baseline: 1.5259x; 1.5259x over previous
//
#include <hip/hip_runtime.h>
#include <hip/hip_bf16.h>

#define S_LEN 4096
#define BATCH 4
#define DMODEL 1024
#define HDIM 128
#define NSLOT 8   // KV chunk slots (fixed chunk = 8 kv-blocks = 512 kv)

typedef __attribute__((ext_vector_type(8))) short short8;
typedef __attribute__((ext_vector_type(4))) short short4v;
typedef __attribute__((ext_vector_type(4))) float float4v;
typedef __attribute__((ext_vector_type(16))) float float16v;
typedef __attribute__((ext_vector_type(4))) int int4v;

#define MASKVAL (-3.0e38f)
#define MINIT   (-1.0e30f)

static __device__ __forceinline__ unsigned short f2bf(float f) {
    __hip_bfloat16 h = __float2bfloat16(f);
    return *reinterpret_cast<unsigned short*>(&h);
}
static __device__ __forceinline__ unsigned short f2h(float f) {
    _Float16 h = (_Float16)f; return *reinterpret_cast<unsigned short*>(&h);
}
static __device__ __forceinline__ float h2f(unsigned short u) {
    _Float16 h = *reinterpret_cast<_Float16*>(&u); return (float)h;
}
static __device__ __forceinline__ short8 ldf(const unsigned short* p) {
    return *reinterpret_cast<const short8*>(p);
}
// raw v_exp_f32: 2^x in one hazard-aware instruction (scores are in log2 units)
static __device__ __forceinline__ float ex2(float x) {
    return __builtin_amdgcn_exp2f(x);
}
// async global->LDS 16B/lane copy of one 1KB fragment (wave-wide)
static __device__ __forceinline__ void gll16(const unsigned short* g,
                                             unsigned short* l) {
    __builtin_amdgcn_global_load_lds(
        (const __attribute__((address_space(1))) unsigned int*)g,
        (__attribute__((address_space(3))) unsigned int*)l, 16, 0, 0);
}
// pack 8 P-values (one 32-kv window half per lane-pair) into MFMA B-frag
static __device__ __forceinline__ short8 pack_p(const float* pv, int hi) {
    unsigned int A  = (unsigned int)f2bf(pv[0]) | ((unsigned int)f2bf(pv[1]) << 16);
    unsigned int Bw = (unsigned int)f2bf(pv[2]) | ((unsigned int)f2bf(pv[3]) << 16);
    unsigned int C  = (unsigned int)f2bf(pv[4]) | ((unsigned int)f2bf(pv[5]) << 16);
    unsigned int D  = (unsigned int)f2bf(pv[6]) | ((unsigned int)f2bf(pv[7]) << 16);
    unsigned int y1 = (unsigned int)__shfl_xor((int)(hi ? A : C), 32);
    unsigned int y2 = (unsigned int)__shfl_xor((int)(hi ? Bw : D), 32);
    int4v pw;
    pw[0] = (int)(hi ? y1 : A);
    pw[1] = (int)(hi ? y2 : Bw);
    pw[2] = (int)(hi ? C : y1);
    pw[3] = (int)(hi ? D : y2);
    union { int4v iv; short8 s; } pu; pu.iv = pw;
    return pu.s;
}

// ---------------------------------------------------------------------------
// Kernel P1: x (S,B,D) fp32 -> xf fragment-linear bf16 (output-coalesced).
// ---------------------------------------------------------------------------
__global__ __launch_bounds__(256) void xprep_kernel(
    const float* __restrict__ x, unsigned short* __restrict__ xf)
{
    int n = blockIdx.x * 256 + threadIdx.x;   // 524288 threads
    int b = n >> 17;
    int rem = n & 131071;
    int sb = rem >> 10;
    int rem2 = rem & 1023;
    int kq = rem2 >> 4;
    int grp = rem2 & 15;
    int lane0 = grp * 4;
    int par = grp >> 3;
    int s0 = lane0 & 31;
    int k = kq * 16 + par * 8;

    short8 hv[4];
#pragma unroll
    for (int r = 0; r < 4; r++) {
        int s = sb * 32 + s0 + r;
        const float* src = &x[((size_t)s * BATCH + b) * DMODEL + k];
        float4 v0 = *reinterpret_cast<const float4*>(src);
        float4 v1 = *reinterpret_cast<const float4*>(src + 4);
        short8 h;
        h[0] = (short)f2bf(v0.x); h[1] = (short)f2bf(v0.y);
        h[2] = (short)f2bf(v0.z); h[3] = (short)f2bf(v0.w);
        h[4] = (short)f2bf(v1.x); h[5] = (short)f2bf(v1.y);
        h[6] = (short)f2bf(v1.z); h[7] = (short)f2bf(v1.w);
        hv[r] = h;
    }
    size_t addr = (((size_t)b * 128 + sb) * 64 + kq) * 512 + (size_t)lane0 * 8;
#pragma unroll
    for (int r = 0; r < 4; r++)
        *reinterpret_cast<short8*>(xf + addr + r * 8) = hv[r];
}

// ---------------------------------------------------------------------------
// Kernel P2: W (H,D) fp32 -> fragment-linear bf16.
// ---------------------------------------------------------------------------
__global__ __launch_bounds__(256) void wprep_kernel(
    const float* __restrict__ Wq, const float* __restrict__ Wk,
    const float* __restrict__ Wv, unsigned short* __restrict__ Wqf,
    unsigned short* __restrict__ Wkf, unsigned short* __restrict__ Wvf)
{
    const int which = blockIdx.y;
    const float* W = (which == 0) ? Wq : (which == 1) ? Wk : Wv;
    unsigned short* Wf = (which == 0) ? Wqf : (which == 1) ? Wkf : Wvf;
    int n = blockIdx.x * 256 + threadIdx.x;   // 16384
    int d = n >> 7, k8 = n & 127;
    const float* src = &W[(size_t)d * DMODEL + k8 * 8];
    float4 v0 = *reinterpret_cast<const float4*>(src);
    float4 v1 = *reinterpret_cast<const float4*>(src + 4);
    short8 h;
    h[0] = (short)f2bf(v0.x); h[1] = (short)f2bf(v0.y);
    h[2] = (short)f2bf(v0.z); h[3] = (short)f2bf(v0.w);
    h[4] = (short)f2bf(v1.x); h[5] = (short)f2bf(v1.y);
    h[6] = (short)f2bf(v1.z); h[7] = (short)f2bf(v1.w);
    size_t addr = (((size_t)(d >> 5)) * 64 + (k8 >> 1)) * 512
                + (size_t)(((d & 31) + 32 * (k8 & 1)) * 8);
    *reinterpret_cast<short8*>(Wf + addr) = h;
}

// ---------------------------------------------------------------------------
// Kernel A: fused QKV GEMM — split-K=2, LDS fp32 combine, depth-1 reg prefetch.
// Q scale folds head_dim^-0.5 AND log2(e) (attn softmax runs in exp2 domain).
// ---------------------------------------------------------------------------
__global__ __launch_bounds__(256) void qkv_gemm_kernel(
    const unsigned short* __restrict__ xf, const unsigned short* __restrict__ Wqf,
    const unsigned short* __restrict__ Wkf, const unsigned short* __restrict__ Wvf,
    unsigned short* __restrict__ Qf, unsigned short* __restrict__ Kf,
    unsigned short* __restrict__ Vf)
{
    __shared__ float cacc[2 * 4096];          // 32KB: 2 tiles x 32s x 128d fp32

    const int t = threadIdx.x;
    const int w = t >> 6;
    const int lane = t & 63;
    const int hi = lane >> 5;
    const int tloc = w & 1;
    const int half = w >> 1;
    const int tile = blockIdx.x * 2 + tloc;
    const int which = tile >> 9;
    const int rem = tile & 511;
    const int b = rem >> 7;
    const int sblk = rem & 127;

    const unsigned short* Wf = (which == 0) ? Wqf : (which == 1) ? Wkf : Wvf;
    const unsigned short* xp =
        xf + (((size_t)b * 128 + sblk) * 64 + half * 32) * 512 + lane * 8;
    const unsigned short* wp = Wf + (size_t)half * 32 * 512 + lane * 8;

    float16v acc[4];
#pragma unroll
    for (int i = 0; i < 4; i++)
#pragma unroll
        for (int r = 0; r < 16; r++) acc[i][r] = 0.f;

    {
        short8 xA = ldf(xp);
        short8 wA[4];
#pragma unroll
        for (int d4 = 0; d4 < 4; d4++) wA[d4] = ldf(wp + (size_t)(d4 * 64) * 512);
        for (int ks = 0; ks < 32; ks++) {
            short8 xB = xA;
            short8 wB[4];
#pragma unroll
            for (int d4 = 0; d4 < 4; d4++) wB[d4] = wA[d4];
            if (ks < 31) {
                xB = ldf(xp + (ks + 1) * 512);
#pragma unroll
                for (int d4 = 0; d4 < 4; d4++)
                    wB[d4] = ldf(wp + (size_t)(d4 * 64 + ks + 1) * 512);
            }
            __builtin_amdgcn_s_setprio(1);
            if (which != 2) {
#pragma unroll
                for (int d4 = 0; d4 < 4; d4++)
                    acc[d4] = __builtin_amdgcn_mfma_f32_32x32x16_bf16(
                        wA[d4], xA, acc[d4], 0, 0, 0);
            } else {
#pragma unroll
                for (int d4 = 0; d4 < 4; d4++)
                    acc[d4] = __builtin_amdgcn_mfma_f32_32x32x16_bf16(
                        xA, wA[d4], acc[d4], 0, 0, 0);
            }
            __builtin_amdgcn_s_setprio(0);
            xA = xB;
#pragma unroll
            for (int d4 = 0; d4 < 4; d4++) wA[d4] = wB[d4];
        }
    }

    float* my = cacc + tloc * 4096;
    if (half == 1) {
#pragma unroll
        for (int db = 0; db < 4; db++)
#pragma unroll
            for (int rc = 0; rc < 4; rc++) {
                float4v v;
#pragma unroll
                for (int j = 0; j < 4; j++) v[j] = acc[db][rc * 4 + j];
                *reinterpret_cast<float4v*>(
                    my + (db * 4 + rc) * 256 + lane * 4) = v;
            }
    }
    __syncthreads();
    if (half != 0) return;

#pragma unroll
    for (int db = 0; db < 4; db++)
#pragma unroll
        for (int rc = 0; rc < 4; rc++) {
            float4v v = *reinterpret_cast<const float4v*>(
                my + (db * 4 + rc) * 256 + lane * 4);
#pragma unroll
            for (int j = 0; j < 4; j++) acc[db][rc * 4 + j] += v[j];
        }

    if (which != 2) {
        unsigned short* Of = (which == 0) ? Qf : Kf;
        // Q: 128^-0.5 * log2(e)
        const float scale = (which == 0) ? 0.12751744f : 1.0f;
#pragma unroll
        for (int db = 0; db < 4; db++)
#pragma unroll
            for (int g = 0; g < 4; g++) {
                int f = db * 2 + (g >> 1);
                size_t addr = (((size_t)b * 128 + sblk) * 8 + f) * 512
                            + (size_t)(((lane & 31) + 32 * (g & 1)) * 8 + 4 * hi);
                short4v ov;
#pragma unroll
                for (int j = 0; j < 4; j++)
                    ov[j] = (short)f2bf(acc[db][g * 4 + j] * scale);
                *reinterpret_cast<short4v*>(Of + addr) = ov;
            }
    } else {
#pragma unroll
        for (int hb = 0; hb < 4; hb++)
#pragma unroll
            for (int g = 0; g < 4; g++) {
                int kt16 = sblk * 2 + (g >> 1);
                size_t addr = (((size_t)b * 256 + kt16) * 4 + hb) * 512
                            + (size_t)(((lane & 31) + 32 * (g & 1)) * 8 + 4 * hi);
                short4v ov;
#pragma unroll
                for (int j = 0; j < 4; j++)
                    ov[j] = (short)f2bf(acc[hb][g * 4 + j]);
                *reinterpret_cast<short4v*>(Vf + addr) = ov;
            }
    }
}

// ---------------------------------------------------------------------------
// Kernel B: causal flash attention — SINGLE-buffer 32KB LDS (4 blocks/CU),
// gll staging, exp2 softmax (R16 verified champion).
// ---------------------------------------------------------------------------
__global__ __launch_bounds__(256) void attn_kernel(
    const unsigned short* __restrict__ Qf, const unsigned short* __restrict__ Kf,
    const unsigned short* __restrict__ Vf, unsigned short* __restrict__ Opart,
    float* __restrict__ Mpart, float* __restrict__ Lpart)
{
    __shared__ unsigned short Kb[8192];   // 16KB: 16 frags x 512
    __shared__ unsigned short Vb[8192];   // 16KB

    const int t = threadIdx.x;
    const int w = t >> 6;
    const int lane = t & 63;
    const int l31 = lane & 31;
    const int hi = lane >> 5;

    // XCD-aware decode + compact heavy-first (qt descending, real chunks only)
    const int i = blockIdx.x;                 // 0..575
    const int xx = i & 7;
    const int b = xx >> 1;
    int j = (i >> 3) * 2 + (xx & 1);          // 0..143
    int qt = 31;
    while (true) {
        int cnt = (qt + 4) >> 2;              // ceil((qt+1)/4) chunks of 8
        if (j < cnt) break;
        j -= cnt; qt--;
    }
    const int c = j;

    const int nkv = 2 * (qt + 1);
    const int lo = c * 8;
    const int hic = min(lo + 8, nkv);

    const int qb = qt * 128;
    const int qrow = qb + w * 32 + l31;

    // Q as B-fragments from Qf (frag-linear)
    const unsigned short* qp =
        Qf + (((size_t)b * 128 + (qt * 4 + w)) * 8) * 512 + lane * 8;
    short8 qf[8];
#pragma unroll
    for (int f = 0; f < 8; f++) qf[f] = ldf(qp + f * 512);

    const unsigned short* kbase =
        Kf + (size_t)b * (S_LEN / 32) * 8 * 512 + lane * 8;
    const unsigned short* vbase =
        Vf + (size_t)b * (S_LEN / 16) * 4 * 512 + lane * 8;

    float m_run = MINIT, l_run = 0.f;
    float16v o[4];
#pragma unroll
    for (int hb = 0; hb < 4; hb++)
#pragma unroll
        for (int r = 0; r < 16; r++) o[hb][r] = 0.f;

    for (int ti = lo; ti < hic; ti++) {
        const int kvb = ti * 64;
        // stage tile ti (wave w stages frags 4w..4w+3 of K and V)
        {
            const unsigned short* kg = kbase + (size_t)ti * 8192;
            const unsigned short* vg = vbase + (size_t)ti * 8192;
#pragma unroll
            for (int jj = 0; jj < 4; jj++) {
                int fi = 4 * w + jj;
                gll16(kg + fi * 512, &Kb[fi * 512]);
                gll16(vg + fi * 512, &Vb[fi * 512]);
            }
        }
        __syncthreads();   // implicit vmcnt(0): staged writes complete

        const unsigned short* Kl = &Kb[0] + lane * 8;
        const unsigned short* Vl = &Vb[0] + lane * 8;

        // S^T = K Q^T from LDS  (scores already in log2 units via Q scale)
        float16v s0, s1;
#pragma unroll
        for (int r = 0; r < 16; r++) { s0[r] = 0.f; s1[r] = 0.f; }
        __builtin_amdgcn_s_setprio(1);
#pragma unroll
        for (int f = 0; f < 8; f++)
            s0 = __builtin_amdgcn_mfma_f32_32x32x16_bf16(
                ldf(Kl + f * 512), qf[f], s0, 0, 0, 0);
#pragma unroll
        for (int f = 0; f < 8; f++)
            s1 = __builtin_amdgcn_mfma_f32_32x32x16_bf16(
                ldf(Kl + (8 + f) * 512), qf[f], s1, 0, 0, 0);
        __builtin_amdgcn_s_setprio(0);

        // causal mask (diagonal band only)
        if (kvb + 63 > qb + w * 32) {
#pragma unroll
            for (int r = 0; r < 16; r++) {
                int kv0 = kvb + (r & 3) + 8 * (r >> 2) + 4 * hi;
                if (kv0 > qrow) s0[r] = MASKVAL;
                if (kv0 + 32 > qrow) s1[r] = MASKVAL;
            }
        }

        // tree max + defer-max rescale (THR=8 in log2 units; P bounded by 256)
        float mx[16];
#pragma unroll
        for (int r = 0; r < 16; r++) mx[r] = fmaxf(s0[r], s1[r]);
#pragma unroll
        for (int st = 8; st >= 1; st >>= 1)
#pragma unroll
            for (int r = 0; r < st; r++) mx[r] = fmaxf(mx[r], mx[r + st]);
        float pmax = fmaxf(mx[0], __shfl_xor(mx[0], 32));
        if (!__all(pmax - m_run <= 8.0f)) {
            float mnew = fmaxf(m_run, pmax);
            float alpha = ex2(m_run - mnew);
            l_run *= alpha;
#pragma unroll
            for (int hb = 0; hb < 4; hb++) o[hb] = o[hb] * alpha;
            m_run = mnew;
        }
#pragma unroll
        for (int r = 0; r < 16; r++) s0[r] = ex2(s0[r] - m_run);
#pragma unroll
        for (int r = 0; r < 16; r++) s1[r] = ex2(s1[r] - m_run);
        float sm[16];
#pragma unroll
        for (int r = 0; r < 16; r++) sm[r] = s0[r] + s1[r];
#pragma unroll
        for (int st = 8; st >= 1; st >>= 1)
#pragma unroll
            for (int r = 0; r < st; r++) sm[r] += sm[r + st];
        l_run += sm[0] + __shfl_xor(sm[0], 32);

        // PV: 4 windows of 16 kv; V frags from LDS
        float t0[8], t1[8], t2[8], t3[8];
#pragma unroll
        for (int jj = 0; jj < 8; jj++) { t0[jj] = s0[jj]; t1[jj] = s0[8 + jj]; }
#pragma unroll
        for (int jj = 0; jj < 8; jj++) { t2[jj] = s1[jj]; t3[jj] = s1[8 + jj]; }

        short8 p0 = pack_p(t0, hi);
        __builtin_amdgcn_s_setprio(1);
#pragma unroll
        for (int hb = 0; hb < 4; hb++)
            o[hb] = __builtin_amdgcn_mfma_f32_32x32x16_bf16(
                ldf(Vl + (0 * 4 + hb) * 512), p0, o[hb], 0, 0, 0);
        short8 p1 = pack_p(t1, hi);
#pragma unroll
        for (int hb = 0; hb < 4; hb++)
            o[hb] = __builtin_amdgcn_mfma_f32_32x32x16_bf16(
                ldf(Vl + (1 * 4 + hb) * 512), p1, o[hb], 0, 0, 0);
        short8 p2 = pack_p(t2, hi);
#pragma unroll
        for (int hb = 0; hb < 4; hb++)
            o[hb] = __builtin_amdgcn_mfma_f32_32x32x16_bf16(
                ldf(Vl + (2 * 4 + hb) * 512), p2, o[hb], 0, 0, 0);
        short8 p3 = pack_p(t3, hi);
#pragma unroll
        for (int hb = 0; hb < 4; hb++)
            o[hb] = __builtin_amdgcn_mfma_f32_32x32x16_bf16(
                ldf(Vl + (3 * 4 + hb) * 512), p3, o[hb], 0, 0, 0);
        __builtin_amdgcn_s_setprio(0);

        __syncthreads();   // all waves done reading before next stage
    }

    // epilogue: normalized fp16 partial + (m,l);  l==0 -> zeros
    const size_t R0 = (size_t)(c * BATCH + b) * S_LEN;
    const float inv = (l_run > 0.f) ? 1.f / l_run : 0.f;
#pragma unroll
    for (int hb = 0; hb < 4; hb++)
#pragma unroll
        for (int g = 0; g < 4; g++) {
            int h0 = hb * 32 + g * 8 + hi * 4;
            short4v ov;
#pragma unroll
            for (int jj = 0; jj < 4; jj++)
                ov[jj] = (short)f2h(o[hb][g * 4 + jj] * inv);
            *reinterpret_cast<short4v*>(&Opart[(R0 + qrow) * HDIM + h0]) = ov;
        }
    if (hi == 0) { Mpart[R0 + qrow] = m_run; Lpart[R0 + qrow] = l_run; }
}

// ---------------------------------------------------------------------------
// Kernel B2: combine partials -> Ob (B,S,H) bf16  (exp2 domain, consistent)
// ---------------------------------------------------------------------------
__global__ __launch_bounds__(256) void combine_kernel(
    const unsigned short* __restrict__ Opart, const float* __restrict__ Mpart,
    const float* __restrict__ Lpart, unsigned short* __restrict__ Ob)
{
    const int BS = BATCH * S_LEN;
    int idx = blockIdx.x * 256 + threadIdx.x;
    int r = idx >> 4, hc = (idx & 15) * 8;
    int q = r & (S_LEN - 1);
    int qt = q >> 7;
    int nkv = 2 * (qt + 1);
    int cnt = (nkv + 7) >> 3;                // # chunks (fixed chunk = 8)

    float m = -INFINITY;
    for (int j = 0; j < cnt; j++) m = fmaxf(m, Mpart[j * BS + r]);
    float wsum = 0.f;
    float acc[8];
#pragma unroll
    for (int e = 0; e < 8; e++) acc[e] = 0.f;
    for (int j = 0; j < cnt; j++) {
        float wj = __builtin_amdgcn_exp2f(Mpart[j * BS + r] - m) * Lpart[j * BS + r];
        wsum += wj;
        short8 o = *reinterpret_cast<const short8*>(
            &Opart[((size_t)j * BS + r) * HDIM + hc]);
#pragma unroll
        for (int e = 0; e < 8; e++) acc[e] += wj * h2f((unsigned short)o[e]);
    }
    float inv = 1.f / wsum;
    short8 ob;
#pragma unroll
    for (int e = 0; e < 8; e++) ob[e] = (short)f2bf(acc[e] * inv);
    *reinterpret_cast<short8*>(&Ob[(size_t)r * HDIM + hc]) = ob;
}

// ---------------------------------------------------------------------------
// Kernel C: output projection, per-batch tiled.
// ---------------------------------------------------------------------------
__global__ __launch_bounds__(256) void out_proj_kernel(
    const unsigned short* __restrict__ Ob, const float* __restrict__ Wo,
    float* __restrict__ out)
{
    __shared__ unsigned short As[128 * 128];
    __shared__ unsigned short Bs[128 * 128];

    const int t = threadIdx.x;
    const int lane = t & 63, w = t >> 6;
    const int l15 = lane & 15, l4 = lane >> 4;
    const int wr = (w >> 1) * 64, wc = (w & 1) * 64;
    const int s0 = blockIdx.x * 128;
    const int d0 = blockIdx.y * 128;
    const int b = blockIdx.z;

#pragma unroll
    for (int p = 0; p < 8; p++) {
        int e = p * 2048 + t * 8;
        int r = e >> 7, h = e & 127;
        short8 v = *reinterpret_cast<const short8*>(
            &Ob[((size_t)b * S_LEN + s0 + r) * HDIM + h]);
        int off = (r * 256 + h * 2) ^ ((r & 7) << 4);
        *reinterpret_cast<short8*>(reinterpret_cast<char*>(As) + off) = v;
    }
#pragma unroll
    for (int p = 0; p < 16; p++) {
        int e = p * 1024 + t * 4;
        int r = e >> 7, h = e & 127;
        float4 v = *reinterpret_cast<const float4*>(&Wo[(size_t)(d0 + r) * HDIM + h]);
        short4v hh;
        hh[0] = (short)f2bf(v.x); hh[1] = (short)f2bf(v.y);
        hh[2] = (short)f2bf(v.z); hh[3] = (short)f2bf(v.w);
        int off = (r * 256 + h * 2) ^ ((r & 7) << 4);
        *reinterpret_cast<short4v*>(reinterpret_cast<char*>(Bs) + off) = hh;
    }
    __syncthreads();

    float4v acc[4][4];
#pragma unroll
    for (int i = 0; i < 4; i++)
#pragma unroll
        for (int j = 0; j < 4; j++) acc[i][j] = (float4v){0.f, 0.f, 0.f, 0.f};

#pragma unroll
    for (int kk = 0; kk < 4; kk++) {
        short8 a[4], bf[4];
#pragma unroll
        for (int mi = 0; mi < 4; mi++) {
            int row = wr + mi * 16 + l15;
            int off = (row * 256 + (kk * 32 + l4 * 8) * 2) ^ ((row & 7) << 4);
            a[mi] = *reinterpret_cast<const short8*>(
                reinterpret_cast<const char*>(As) + off);
        }
#pragma unroll
        for (int ni = 0; ni < 4; ni++) {
            int row = wc + ni * 16 + l15;
            int off = (row * 256 + (kk * 32 + l4 * 8) * 2) ^ ((row & 7) << 4);
            bf[ni] = *reinterpret_cast<const short8*>(
                reinterpret_cast<const char*>(Bs) + off);
        }
#pragma unroll
        for (int mi = 0; mi < 4; mi++)
#pragma unroll
            for (int ni = 0; ni < 4; ni++)
                acc[mi][ni] = __builtin_amdgcn_mfma_f32_16x16x32_bf16(
                    a[mi], bf[ni], acc[mi][ni], 0, 0, 0);
    }

#pragma unroll
    for (int mi = 0; mi < 4; mi++)
#pragma unroll
        for (int ni = 0; ni < 4; ni++)
#pragma unroll
            for (int r = 0; r < 4; r++) {
                int s = s0 + wr + mi * 16 + l4 * 4 + r;
                int d = d0 + wc + ni * 16 + l15;
                out[((size_t)s * BATCH + b) * DMODEL + d] = acc[mi][ni][r];
            }
}

// ---------------------------------------------------------------------------
extern "C" void kernel_launch(void* const* d_in, const int* in_sizes, int n_in,
                              void* d_out, int out_size, void* d_ws, size_t ws_size,
                              hipStream_t stream) {
    const float* x  = (const float*)d_in[0];
    const float* Wq = (const float*)d_in[1];
    const float* Wk = (const float*)d_in[2];
    const float* Wv = (const float*)d_in[3];
    const float* Wo = (const float*)d_in[4];
    float* out = (float*)d_out;

    const size_t BS = (size_t)BATCH * S_LEN;               // 16384
    // Region 0 (32MB): xf during prep+gemm, then Opart (8 slots, disjoint lifetimes)
    unsigned short* xf    = (unsigned short*)d_ws;               // 32 MB
    unsigned short* Opart = (unsigned short*)d_ws;               // 32 MB fp16
    float* Mpart = (float*)((char*)d_ws + (32u << 20));          // 512 KB
    float* Lpart = Mpart + NSLOT * BS;                           // 512 KB
    // After 33MB:
    unsigned short* Wqf = (unsigned short*)((char*)d_ws + (33u << 20));
    unsigned short* Wkf = Wqf + 131072;
    unsigned short* Wvf = Wkf + 131072;
    unsigned short* Qf  = Wvf + 131072;                          // 4 MB each
    unsigned short* Kf  = Qf + 2097152;
    unsigned short* Vf  = Kf + 2097152;
    unsigned short* Ob  = Vf + 2097152;

    xprep_kernel<<<2048, 256, 0, stream>>>(x, xf);
    wprep_kernel<<<dim3(64, 3), 256, 0, stream>>>(Wq, Wk, Wv, Wqf, Wkf, Wvf);
    qkv_gemm_kernel<<<768, 256, 0, stream>>>(xf, Wqf, Wkf, Wvf, Qf, Kf, Vf);
    attn_kernel<<<576, 256, 0, stream>>>(Qf, Kf, Vf, Opart, Mpart, Lpart);
    combine_kernel<<<1024, 256, 0, stream>>>(Opart, Mpart, Lpart, Ob);
    out_proj_kernel<<<dim3(32, 8, BATCH), 256, 0, stream>>>(Ob, Wo, out);
}